// Round 1
// baseline (203.411 us; speedup 1.0000x reference)
//
#include <hip/hip_runtime.h>
#include <hip/hip_bf16.h>
#include <math.h>

// Problem: B=4, N=2048, M=64, L=64, all fp32.
// out[bn,l] = sigmoid( (tr[bn,l]*kr[l]+br[l]) * (kl[l]*S[bn,l] + bl[l]*A[bn]) )
//   S[bn,l] = sum_m nl[bn,m,l]*a[bn,m],  A[bn] = sum_m a[bn,m]
//
// One wave per bn-tile (64x64 floats = 16 KiB). Lane i: row m=i>>4, col-group
// i&15 (float4). 16 unrolled iterations sweep all 64 rows. Memory-bound:
// ~134 MiB total traffic -> ~21 us floor at 6.3 TB/s.

#define LDIM 64
#define MDIM 64

__global__ __launch_bounds__(256) void slg_fused_kernel(
    const float* __restrict__ tr,   // (BN, L)
    const float* __restrict__ nl,   // (BN, M, L)
    const float* __restrict__ a,    // (BN, M)
    const float* __restrict__ kl,   // (L)
    const float* __restrict__ bl,   // (L)
    const float* __restrict__ kr,   // (L)
    const float* __restrict__ br,   // (L)
    float* __restrict__ out,        // (BN, L)
    int BN)
{
    const int waves_per_block = blockDim.x >> 6;
    const int bn = blockIdx.x * waves_per_block + (threadIdx.x >> 6);
    const int lane = threadIdx.x & 63;
    if (bn >= BN) return;

    const float* nlp = nl + (size_t)bn * (MDIM * LDIM);
    const float a_lane = a[(size_t)bn * MDIM + lane];

    const int colg = lane & 15;   // l-group: l = colg*4 + c
    const int row0 = lane >> 4;   // base row 0..3

    // Pre-gather the 16 a[m] values this lane needs (m = row0 + 4k).
    float am[16];
#pragma unroll
    for (int k = 0; k < 16; ++k)
        am[k] = __shfl(a_lane, row0 + 4 * k, 64);

    float4 acc = make_float4(0.f, 0.f, 0.f, 0.f);
#pragma unroll
    for (int k = 0; k < 16; ++k) {
        const int m = row0 + 4 * k;
        const float4 v =
            *reinterpret_cast<const float4*>(nlp + m * LDIM + colg * 4);
        acc.x = fmaf(am[k], v.x, acc.x);
        acc.y = fmaf(am[k], v.y, acc.y);
        acc.z = fmaf(am[k], v.z, acc.z);
        acc.w = fmaf(am[k], v.w, acc.w);
    }

    // Reduce across the 4 lanes sharing colg (lanes i, i^16, i^32, i^48).
#pragma unroll
    for (int off = 16; off <= 32; off <<= 1) {
        acc.x += __shfl_xor(acc.x, off, 64);
        acc.y += __shfl_xor(acc.y, off, 64);
        acc.z += __shfl_xor(acc.z, off, 64);
        acc.w += __shfl_xor(acc.w, off, 64);
    }

    // Full-wave sum of a[bn,:].
    float asum = a_lane;
#pragma unroll
    for (int off = 1; off <= 32; off <<= 1)
        asum += __shfl_xor(asum, off, 64);

    if (lane < 16) {
        const int l0 = lane * 4;
        const float4 t  = *reinterpret_cast<const float4*>(tr + (size_t)bn * LDIM + l0);
        const float4 K  = *reinterpret_cast<const float4*>(kl + l0);
        const float4 Bl = *reinterpret_cast<const float4*>(bl + l0);
        const float4 Kr = *reinterpret_cast<const float4*>(kr + l0);
        const float4 Br = *reinterpret_cast<const float4*>(br + l0);

        float wx = (t.x * Kr.x + Br.x) * (K.x * acc.x + Bl.x * asum);
        float wy = (t.y * Kr.y + Br.y) * (K.y * acc.y + Bl.y * asum);
        float wz = (t.z * Kr.z + Br.z) * (K.z * acc.z + Bl.z * asum);
        float ww = (t.w * Kr.w + Br.w) * (K.w * acc.w + Bl.w * asum);

        float4 o;
        o.x = 1.0f / (1.0f + __expf(-wx));
        o.y = 1.0f / (1.0f + __expf(-wy));
        o.z = 1.0f / (1.0f + __expf(-wz));
        o.w = 1.0f / (1.0f + __expf(-ww));

        *reinterpret_cast<float4*>(out + (size_t)bn * LDIM + l0) = o;
    }
}

extern "C" void kernel_launch(void* const* d_in, const int* in_sizes, int n_in,
                              void* d_out, int out_size, void* d_ws, size_t ws_size,
                              hipStream_t stream) {
    const float* tr = (const float*)d_in[0];  // (B,N,L)
    const float* nl = (const float*)d_in[1];  // (B,N,M,L)
    const float* a  = (const float*)d_in[2];  // (B,N,M)
    const float* kl = (const float*)d_in[3];  // (L)
    const float* bl = (const float*)d_in[4];  // (L)
    const float* kr = (const float*)d_in[5];  // (L)
    const float* br = (const float*)d_in[6];  // (L)
    float* out = (float*)d_out;

    const int BN = in_sizes[0] / LDIM;        // B*N = 8192
    const int block = 256;                    // 4 waves -> 4 bn-tiles per block
    const int grid = (BN + 3) / 4;

    slg_fused_kernel<<<grid, block, 0, stream>>>(tr, nl, a, kl, bl, kr, br, out, BN);
}

// Round 2
// 194.847 us; speedup vs baseline: 1.0440x; 1.0440x over previous
//
#include <hip/hip_runtime.h>
#include <hip/hip_bf16.h>
#include <math.h>

// Problem: B=4, N=2048, M=64, L=64, all fp32.
// out[bn,l] = sigmoid( (tr[bn,l]*kr[l]+br[l]) * (kl[l]*S[bn,l] + bl[l]*A[bn]) )
//   S[bn,l] = sum_m nl[bn,m,l]*a[bn,m],  A[bn] = sum_m a[bn,m]
//
// One wave per bn-tile (64x64 floats = 16 KiB). Lane i: rows m = (i>>4)+4k,
// col-group i&15 (float4). Fully coalesced 16 B/lane loads; wave covers
// 1 KiB contiguous per iteration. Memory floor: ~134 MiB / 6.3 TB/s ~= 21 us.
// R1: nontemporal load/store hints (pure streaming, read-once/write-once).

#define LDIM 64
#define MDIM 64

typedef float v4f __attribute__((ext_vector_type(4)));

__global__ __launch_bounds__(256) void slg_fused_kernel(
    const float* __restrict__ tr,   // (BN, L)
    const float* __restrict__ nl,   // (BN, M, L)
    const float* __restrict__ a,    // (BN, M)
    const float* __restrict__ kl,   // (L)
    const float* __restrict__ bl,   // (L)
    const float* __restrict__ kr,   // (L)
    const float* __restrict__ br,   // (L)
    float* __restrict__ out,        // (BN, L)
    int BN)
{
    const int waves_per_block = blockDim.x >> 6;
    const int bn = blockIdx.x * waves_per_block + (threadIdx.x >> 6);
    const int lane = threadIdx.x & 63;
    if (bn >= BN) return;

    const float* nlp = nl + (size_t)bn * (MDIM * LDIM);
    const float a_lane = a[(size_t)bn * MDIM + lane];

    const int colg = lane & 15;   // l-group: l = colg*4 + c
    const int row0 = lane >> 4;   // base row 0..3

    // Pre-gather the 16 a[m] values this lane needs (m = row0 + 4k).
    float am[16];
#pragma unroll
    for (int k = 0; k < 16; ++k)
        am[k] = __shfl(a_lane, row0 + 4 * k, 64);

    v4f acc = {0.f, 0.f, 0.f, 0.f};
#pragma unroll
    for (int k = 0; k < 16; ++k) {
        const int m = row0 + 4 * k;
        const v4f v = __builtin_nontemporal_load(
            reinterpret_cast<const v4f*>(nlp + m * LDIM + colg * 4));
        acc.x = fmaf(am[k], v.x, acc.x);
        acc.y = fmaf(am[k], v.y, acc.y);
        acc.z = fmaf(am[k], v.z, acc.z);
        acc.w = fmaf(am[k], v.w, acc.w);
    }

    // Reduce across the 4 lanes sharing colg (lanes i, i^16, i^32, i^48).
#pragma unroll
    for (int off = 16; off <= 32; off <<= 1) {
        acc.x += __shfl_xor(acc.x, off, 64);
        acc.y += __shfl_xor(acc.y, off, 64);
        acc.z += __shfl_xor(acc.z, off, 64);
        acc.w += __shfl_xor(acc.w, off, 64);
    }

    // Full-wave sum of a[bn,:].
    float asum = a_lane;
#pragma unroll
    for (int off = 1; off <= 32; off <<= 1)
        asum += __shfl_xor(asum, off, 64);

    if (lane < 16) {
        const int l0 = lane * 4;
        const float4 t  = *reinterpret_cast<const float4*>(tr + (size_t)bn * LDIM + l0);
        const float4 K  = *reinterpret_cast<const float4*>(kl + l0);
        const float4 Bl = *reinterpret_cast<const float4*>(bl + l0);
        const float4 Kr = *reinterpret_cast<const float4*>(kr + l0);
        const float4 Br = *reinterpret_cast<const float4*>(br + l0);

        float wx = (t.x * Kr.x + Br.x) * (K.x * acc.x + Bl.x * asum);
        float wy = (t.y * Kr.y + Br.y) * (K.y * acc.y + Bl.y * asum);
        float wz = (t.z * Kr.z + Br.z) * (K.z * acc.z + Bl.z * asum);
        float ww = (t.w * Kr.w + Br.w) * (K.w * acc.w + Bl.w * asum);

        v4f o;
        o.x = 1.0f / (1.0f + __expf(-wx));
        o.y = 1.0f / (1.0f + __expf(-wy));
        o.z = 1.0f / (1.0f + __expf(-wz));
        o.w = 1.0f / (1.0f + __expf(-ww));

        __builtin_nontemporal_store(
            o, reinterpret_cast<v4f*>(out + (size_t)bn * LDIM + l0));
    }
}

extern "C" void kernel_launch(void* const* d_in, const int* in_sizes, int n_in,
                              void* d_out, int out_size, void* d_ws, size_t ws_size,
                              hipStream_t stream) {
    const float* tr = (const float*)d_in[0];  // (B,N,L)
    const float* nl = (const float*)d_in[1];  // (B,N,M,L)
    const float* a  = (const float*)d_in[2];  // (B,N,M)
    const float* kl = (const float*)d_in[3];  // (L)
    const float* bl = (const float*)d_in[4];  // (L)
    const float* kr = (const float*)d_in[5];  // (L)
    const float* br = (const float*)d_in[6];  // (L)
    float* out = (float*)d_out;

    const int BN = in_sizes[0] / LDIM;        // B*N = 8192
    const int block = 256;                    // 4 waves -> 4 bn-tiles per block
    const int grid = (BN + 3) / 4;

    slg_fused_kernel<<<grid, block, 0, stream>>>(tr, nl, a, kl, bl, kr, br, out, BN);
}